// Round 1
// baseline (432.162 us; speedup 1.0000x reference)
//
#include <hip/hip_runtime.h>

typedef __attribute__((ext_vector_type(8))) short short8;   // 8 bf16 (4 VGPRs) MFMA A/B frag
typedef __attribute__((ext_vector_type(4))) float f32x4;    // MFMA C/D frag

constexpr int B_ROWS   = 524288;
constexpr int ROWTILES = B_ROWS / 64;   // 8192 tiles of 64 rows
constexpr int GRID     = 2048;
constexpr int ITERS    = ROWTILES / GRID;   // 4 tiles per block
constexpr float L2E2   = 2.8853900817779268f;  // 2*log2(e)

union V16 { uint4 u; short8 s; };

// round-half-up bf16 pair pack: (bits+0x8000)>>16, two elems -> one u32 via v_perm.
__device__ __forceinline__ unsigned pk(float lo, float hi) {
  const unsigned a = __float_as_uint(lo) + 0x8000u;
  const unsigned b = __float_as_uint(hi) + 0x8000u;
  return __builtin_amdgcn_perm(b, a, 0x07060302u);  // dst = [a.hi16, b.hi16]
}

__device__ __forceinline__ V16 pk8(f32x4 a, f32x4 b) {
  V16 v;
  v.u.x = pk(a[0], a[1]); v.u.y = pk(a[2], a[3]);
  v.u.z = pk(b[0], b[1]); v.u.w = pk(b[2], b[3]);
  return v;
}

// Single-barrier software pipeline:
//   iter i: compute tile i from xb[p] -> obuf[p]; pack regs(tile i+1) -> xb[p^1];
//           __syncthreads(); coalesced store obuf[p]; global-load tile i+2 -> regs.
// C[n,b] = sum_i (L*W1[n,i])*x[b,i]; out[b,k] = 1 - 1/(exp2(L*S)+1),
// S = b2 + sum_h w2 - sum_h 2*w2/(exp2(acc + L*b1)+1)   [folded tanh algebra]
//
// LDS budget: xb 16384B + ob 4096B = 20480B = 160KiB/8 EXACTLY -> 8 blocks/CU
// resident (was 21504B -> 7 blocks/CU -> a 256-block straggler round that
// ~doubled kernel time). launch_bounds(256,8) pins VGPR<=64 (8 waves/EU cap).
__global__ __launch_bounds__(256, 8) void fused_mlp8(
    const float* __restrict__ x, const float* __restrict__ W1,
    const float* __restrict__ b1, const float* __restrict__ W2,
    const float* __restrict__ b2, float* __restrict__ out) {

  // x: 2 buffers x 64 rows x 8 chunks(16B); chunk c of row r at r*8 + (c ^ (r&7))
  __shared__ V16  xb[2][512];
  // out staging: 64 rows x 8 floats, stride 8 (not 10). float2 slot is
  // XOR-swizzled by (row>>2)&3 so the 16 writer lanes of a wave hit 16
  // distinct bank-pairs (conflict-free), same as the old stride-10 pad.
  __shared__ float ob[2][64 * 8];

  const int tid  = threadIdx.x;
  const int wave = tid >> 6;
  const int lane = tid & 63;
  const int m16  = lane & 15;
  const int q    = lane >> 4;

  // write-side swizzled float2 column: (r>>2)&3 == m16>>2 for all tt -> invariant
  const int ocol = (wave ^ (m16 >> 2)) * 2;

  // ---- W1 A-fragments (scaled by L2E2): lane holds rows n=(4w+mt)*16+m16
  short8 w1f[4][2];
#pragma unroll
  for (int mt = 0; mt < 4; ++mt) {
    const int n = (wave * 4 + mt) * 16 + m16;
#pragma unroll
    for (int ks = 0; ks < 2; ++ks) {
      const float* p = W1 + n * 64 + ks * 32 + q * 8;
      const f32x4 u0 = *(const f32x4*)p, u1 = *(const f32x4*)(p + 4);
      f32x4 s0, s1;
#pragma unroll
      for (int r = 0; r < 4; ++r) { s0[r] = L2E2 * u0[r]; s1[r] = L2E2 * u1[r]; }
      w1f[mt][ks] = pk8(s0, s1).s;
    }
  }

  // ---- folded per-lane constants for C-layout rows n0 = (4w+mt)*16 + 4q
  f32x4 kb1[4], w2m[4];
  float sw2[2] = {0.f, 0.f};
#pragma unroll
  for (int mt = 0; mt < 4; ++mt) {
    const int n0 = (wave * 4 + mt) * 16 + q * 4;
    const f32x4 b1x = *(const f32x4*)(b1 + n0);
    const f32x4 w2x = *(const f32x4*)(W2 + n0);
#pragma unroll
    for (int r = 0; r < 4; ++r) {
      kb1[mt][r] = L2E2 * b1x[r];
      w2m[mt][r] = -2.0f * w2x[r];
      sw2[mt >> 1] += w2x[r];
    }
  }
  float KSb[2];
#pragma unroll
  for (int j = 0; j < 2; ++j) {
    float s = sw2[j];
    s += __shfl_xor(s, 16);
    s += __shfl_xor(s, 32);
    KSb[j] = L2E2 * (s + b2[wave * 2 + j]);
  }

  // ---- staging geometry: thread covers row=tid>>2, cols seg*16..+15 (64B)
  const int srow = tid >> 2;
  const int seg  = tid & 3;
  const int sw   = srow & 7;
  const float* gbase = x + (long)srow * 64 + seg * 16;

  // ---- prologue: tile0 -> xb[0]; tile1 -> regs
  f32x4 pf[4];
#pragma unroll
  for (int c = 0; c < 4; ++c)
    pf[c] = *(const f32x4*)(gbase + (long)blockIdx.x * 4096 + c * 4);
  xb[0][srow * 8 + ((seg * 2)     ^ sw)] = pk8(pf[0], pf[1]);
  xb[0][srow * 8 + ((seg * 2 + 1) ^ sw)] = pk8(pf[2], pf[3]);
#pragma unroll
  for (int c = 0; c < 4; ++c)
    pf[c] = *(const f32x4*)(gbase + ((long)blockIdx.x + GRID) * 4096 + c * 4);
  __syncthreads();

#pragma unroll
  for (int i = 0; i < ITERS; ++i) {
    const int p = i & 1;
    const long tile = (long)blockIdx.x + (long)i * GRID;

    // ---- compute tile i from xb[p] -> ob[p]
#pragma unroll
    for (int tt = 0; tt < 4; ++tt) {
      const int r   = tt * 16 + m16;
      const int rsw = r & 7;
      const short8 xf0 = xb[p][r * 8 + (q       ^ rsw)].s;
      const short8 xf1 = xb[p][r * 8 + ((q + 4) ^ rsw)].s;

      f32x4 acc[4];
#pragma unroll
      for (int mt = 0; mt < 4; ++mt) {
        f32x4 z = { 0.f, 0.f, 0.f, 0.f };
        z = __builtin_amdgcn_mfma_f32_16x16x32_bf16(w1f[mt][0], xf0, z, 0, 0, 0);
        z = __builtin_amdgcn_mfma_f32_16x16x32_bf16(w1f[mt][1], xf1, z, 0, 0, 0);
        acc[mt] = z;
      }

      float o0 = 0.f, o1 = 0.f;
#pragma unroll
      for (int j = 0; j < 2; ++j) {
        float P = 0.f;
#pragma unroll
        for (int t = 0; t < 2; ++t) {
          const int mt = j * 2 + t;
#pragma unroll
          for (int rr = 0; rr < 4; ++rr) {
            const float e = __builtin_amdgcn_exp2f(acc[mt][rr] + kb1[mt][rr]);
            P = __builtin_fmaf(w2m[mt][rr], __builtin_amdgcn_rcpf(e + 1.0f), P);
          }
        }
        P += __shfl_xor(P, 16);
        P += __shfl_xor(P, 32);
        const float arg = __builtin_fmaf(P, L2E2, KSb[j]);
        const float o = 1.0f - __builtin_amdgcn_rcpf(
            __builtin_amdgcn_exp2f(arg) + 1.0f);
        if (j == 0) o0 = o; else o1 = o;
      }

      if (q == 0) {  // stage to LDS (swizzled stride-8 rows: conflict-free)
        float2 st; st.x = o0; st.y = o1;
        *(float2*)&ob[p][r * 8 + ocol] = st;
      }
    }

    // ---- pack tile i+1 regs -> xb[p^1] (overlaps compute; pre-barrier)
    if (i + 1 < ITERS) {
      xb[p ^ 1][srow * 8 + ((seg * 2)     ^ sw)] = pk8(pf[0], pf[1]);
      xb[p ^ 1][srow * 8 + ((seg * 2 + 1) ^ sw)] = pk8(pf[2], pf[3]);
    }

    __syncthreads();   // the ONLY barrier per iteration

    // ---- coalesced store of tile i (thread t -> row t>>2, floats (t&3)*2..+1)
    {
      const int orow = tid >> 2;
      const int rcol = ((tid & 3) ^ ((tid >> 4) & 3)) * 2;   // un-swizzle
      const float2 v = *(const float2*)&ob[p][orow * 8 + rcol];
      *(float2*)(out + (tile * 64 + orow) * 8 + (tid & 3) * 2) = v;
    }

    // ---- issue tile i+2 loads; consumed at iteration i+1's pack
    if (i + 2 < ITERS) {
      const float* gp = gbase + (tile + 2 * GRID) * 4096;
#pragma unroll
      for (int c = 0; c < 4; ++c) pf[c] = *(const f32x4*)(gp + c * 4);
    }
  }
}

extern "C" void kernel_launch(void* const* d_in, const int* in_sizes, int n_in,
                              void* d_out, int out_size, void* d_ws, size_t ws_size,
                              hipStream_t stream) {
  const float* x  = (const float*)d_in[0];
  const float* W1 = (const float*)d_in[1];
  const float* b1 = (const float*)d_in[2];
  const float* W2 = (const float*)d_in[3];
  const float* b2 = (const float*)d_in[4];
  float* out = (float*)d_out;
  fused_mlp8<<<GRID, 256, 0, stream>>>(x, W1, b1, W2, b2, out);
}

// Round 2
// 212.427 us; speedup vs baseline: 2.0344x; 2.0344x over previous
//
#include <hip/hip_runtime.h>

typedef __attribute__((ext_vector_type(8))) short short8;   // 8 bf16 (4 VGPRs) MFMA A/B frag
typedef __attribute__((ext_vector_type(4))) float f32x4;    // MFMA C/D frag

constexpr int B_ROWS   = 524288;
constexpr int ROWTILES = B_ROWS / 64;   // 8192 tiles of 64 rows
constexpr int GRID     = 2048;
constexpr int ITERS    = ROWTILES / GRID;   // 4 tiles per block
constexpr float L2E2   = 2.8853900817779268f;  // 2*log2(e)

union V16 { uint4 u; short8 s; };

// round-half-up bf16 pair pack: (bits+0x8000)>>16, two elems -> one u32 via v_perm.
__device__ __forceinline__ unsigned pk(float lo, float hi) {
  const unsigned a = __float_as_uint(lo) + 0x8000u;
  const unsigned b = __float_as_uint(hi) + 0x8000u;
  return __builtin_amdgcn_perm(b, a, 0x07060302u);  // dst = [a.hi16, b.hi16]
}

__device__ __forceinline__ V16 pk8(f32x4 a, f32x4 b) {
  V16 v;
  v.u.x = pk(a[0], a[1]); v.u.y = pk(a[2], a[3]);
  v.u.z = pk(b[0], b[1]); v.u.w = pk(b[2], b[3]);
  return v;
}

// Single-barrier software pipeline:
//   iter i: compute tile i from xb[p] -> obuf[p]; pack regs(tile i+1) -> xb[p^1];
//           __syncthreads(); coalesced store obuf[p]; global-load tile i+2 -> regs.
// C[n,b] = sum_i (L*W1[n,i])*x[b,i]; out[b,k] = 1 - 1/(exp2(L*S)+1),
// S = b2 + sum_h w2 - sum_h 2*w2/(exp2(acc + L*b1)+1)   [folded tanh algebra]
//
// LDS budget: xb 16384B + ob 4096B = 20480B = 160KiB/8 EXACTLY -> 8 blocks/CU
// resident (21504B gave 7 blocks/CU -> 256-block straggler round ~doubling time).
// launch_bounds MUST stay (256,4): (256,8) clamps the allocator to 32 arch-VGPRs
// (unified-file split accounting) and spills everything -> 833MB scratch fetch,
// 294us/dispatch (round-1 regression). This body compiles to exactly 64 VGPRs
// under (256,4), and VGPR=64 still permits the full 32 waves/CU.
__global__ __launch_bounds__(256, 4) void fused_mlp8(
    const float* __restrict__ x, const float* __restrict__ W1,
    const float* __restrict__ b1, const float* __restrict__ W2,
    const float* __restrict__ b2, float* __restrict__ out) {

  // x: 2 buffers x 64 rows x 8 chunks(16B); chunk c of row r at r*8 + (c ^ (r&7))
  __shared__ V16  xb[2][512];
  // out staging: 64 rows x 8 floats, stride 8 (not 10). float2 slot is
  // XOR-swizzled by (row>>2)&3 so the 16 writer lanes of a wave hit 16
  // distinct bank-pairs (conflict-free), same as the old stride-10 pad.
  __shared__ float ob[2][64 * 8];

  const int tid  = threadIdx.x;
  const int wave = tid >> 6;
  const int lane = tid & 63;
  const int m16  = lane & 15;
  const int q    = lane >> 4;

  // write-side swizzled float2 column: (r>>2)&3 == m16>>2 for all tt -> invariant
  const int ocol = (wave ^ (m16 >> 2)) * 2;

  // ---- W1 A-fragments (scaled by L2E2): lane holds rows n=(4w+mt)*16+m16
  short8 w1f[4][2];
#pragma unroll
  for (int mt = 0; mt < 4; ++mt) {
    const int n = (wave * 4 + mt) * 16 + m16;
#pragma unroll
    for (int ks = 0; ks < 2; ++ks) {
      const float* p = W1 + n * 64 + ks * 32 + q * 8;
      const f32x4 u0 = *(const f32x4*)p, u1 = *(const f32x4*)(p + 4);
      f32x4 s0, s1;
#pragma unroll
      for (int r = 0; r < 4; ++r) { s0[r] = L2E2 * u0[r]; s1[r] = L2E2 * u1[r]; }
      w1f[mt][ks] = pk8(s0, s1).s;
    }
  }

  // ---- folded per-lane constants for C-layout rows n0 = (4w+mt)*16 + 4q
  f32x4 kb1[4], w2m[4];
  float sw2[2] = {0.f, 0.f};
#pragma unroll
  for (int mt = 0; mt < 4; ++mt) {
    const int n0 = (wave * 4 + mt) * 16 + q * 4;
    const f32x4 b1x = *(const f32x4*)(b1 + n0);
    const f32x4 w2x = *(const f32x4*)(W2 + n0);
#pragma unroll
    for (int r = 0; r < 4; ++r) {
      kb1[mt][r] = L2E2 * b1x[r];
      w2m[mt][r] = -2.0f * w2x[r];
      sw2[mt >> 1] += w2x[r];
    }
  }
  float KSb[2];
#pragma unroll
  for (int j = 0; j < 2; ++j) {
    float s = sw2[j];
    s += __shfl_xor(s, 16);
    s += __shfl_xor(s, 32);
    KSb[j] = L2E2 * (s + b2[wave * 2 + j]);
  }

  // ---- staging geometry: thread covers row=tid>>2, cols seg*16..+15 (64B)
  const int srow = tid >> 2;
  const int seg  = tid & 3;
  const int sw   = srow & 7;
  const float* gbase = x + (long)srow * 64 + seg * 16;

  // ---- prologue: tile0 -> xb[0]; tile1 -> regs
  f32x4 pf[4];
#pragma unroll
  for (int c = 0; c < 4; ++c)
    pf[c] = *(const f32x4*)(gbase + (long)blockIdx.x * 4096 + c * 4);
  xb[0][srow * 8 + ((seg * 2)     ^ sw)] = pk8(pf[0], pf[1]);
  xb[0][srow * 8 + ((seg * 2 + 1) ^ sw)] = pk8(pf[2], pf[3]);
#pragma unroll
  for (int c = 0; c < 4; ++c)
    pf[c] = *(const f32x4*)(gbase + ((long)blockIdx.x + GRID) * 4096 + c * 4);
  __syncthreads();

#pragma unroll
  for (int i = 0; i < ITERS; ++i) {
    const int p = i & 1;
    const long tile = (long)blockIdx.x + (long)i * GRID;

    // ---- compute tile i from xb[p] -> ob[p]
#pragma unroll
    for (int tt = 0; tt < 4; ++tt) {
      const int r   = tt * 16 + m16;
      const int rsw = r & 7;
      const short8 xf0 = xb[p][r * 8 + (q       ^ rsw)].s;
      const short8 xf1 = xb[p][r * 8 + ((q + 4) ^ rsw)].s;

      f32x4 acc[4];
#pragma unroll
      for (int mt = 0; mt < 4; ++mt) {
        f32x4 z = { 0.f, 0.f, 0.f, 0.f };
        z = __builtin_amdgcn_mfma_f32_16x16x32_bf16(w1f[mt][0], xf0, z, 0, 0, 0);
        z = __builtin_amdgcn_mfma_f32_16x16x32_bf16(w1f[mt][1], xf1, z, 0, 0, 0);
        acc[mt] = z;
      }

      float o0 = 0.f, o1 = 0.f;
#pragma unroll
      for (int j = 0; j < 2; ++j) {
        float P = 0.f;
#pragma unroll
        for (int t = 0; t < 2; ++t) {
          const int mt = j * 2 + t;
#pragma unroll
          for (int rr = 0; rr < 4; ++rr) {
            const float e = __builtin_amdgcn_exp2f(acc[mt][rr] + kb1[mt][rr]);
            P = __builtin_fmaf(w2m[mt][rr], __builtin_amdgcn_rcpf(e + 1.0f), P);
          }
        }
        P += __shfl_xor(P, 16);
        P += __shfl_xor(P, 32);
        const float arg = __builtin_fmaf(P, L2E2, KSb[j]);
        const float o = 1.0f - __builtin_amdgcn_rcpf(
            __builtin_amdgcn_exp2f(arg) + 1.0f);
        if (j == 0) o0 = o; else o1 = o;
      }

      if (q == 0) {  // stage to LDS (swizzled stride-8 rows: conflict-free)
        float2 st; st.x = o0; st.y = o1;
        *(float2*)&ob[p][r * 8 + ocol] = st;
      }
    }

    // ---- pack tile i+1 regs -> xb[p^1] (overlaps compute; pre-barrier)
    if (i + 1 < ITERS) {
      xb[p ^ 1][srow * 8 + ((seg * 2)     ^ sw)] = pk8(pf[0], pf[1]);
      xb[p ^ 1][srow * 8 + ((seg * 2 + 1) ^ sw)] = pk8(pf[2], pf[3]);
    }

    __syncthreads();   // the ONLY barrier per iteration

    // ---- coalesced store of tile i (thread t -> row t>>2, floats (t&3)*2..+1)
    {
      const int orow = tid >> 2;
      const int rcol = ((tid & 3) ^ ((tid >> 4) & 3)) * 2;   // un-swizzle
      const float2 v = *(const float2*)&ob[p][orow * 8 + rcol];
      *(float2*)(out + (tile * 64 + orow) * 8 + (tid & 3) * 2) = v;
    }

    // ---- issue tile i+2 loads; consumed at iteration i+1's pack
    if (i + 2 < ITERS) {
      const float* gp = gbase + (tile + 2 * GRID) * 4096;
#pragma unroll
      for (int c = 0; c < 4; ++c) pf[c] = *(const f32x4*)(gp + c * 4);
    }
  }
}

extern "C" void kernel_launch(void* const* d_in, const int* in_sizes, int n_in,
                              void* d_out, int out_size, void* d_ws, size_t ws_size,
                              hipStream_t stream) {
  const float* x  = (const float*)d_in[0];
  const float* W1 = (const float*)d_in[1];
  const float* b1 = (const float*)d_in[2];
  const float* W2 = (const float*)d_in[3];
  const float* b2 = (const float*)d_in[4];
  float* out = (float*)d_out;
  fused_mlp8<<<GRID, 256, 0, stream>>>(x, W1, b1, W2, b2, out);
}

// Round 3
// 208.764 us; speedup vs baseline: 2.0701x; 1.0175x over previous
//
#include <hip/hip_runtime.h>

typedef __attribute__((ext_vector_type(8))) short short8;   // 8 bf16 (4 VGPRs) MFMA A/B frag
typedef __attribute__((ext_vector_type(4))) float f32x4;    // MFMA C/D frag

constexpr int B_ROWS   = 524288;
constexpr int ROWTILES = B_ROWS / 64;   // 8192 tiles of 64 rows
constexpr int GRID     = 2048;
constexpr int ITERS    = ROWTILES / GRID;   // 4 tiles per block
constexpr float L2E2   = 2.8853900817779268f;  // 2*log2(e)

union V16 { uint4 u; short8 s; };

// round-half-up bf16 pair pack: (bits+0x8000)>>16, two elems -> one u32 via v_perm.
__device__ __forceinline__ unsigned pk(float lo, float hi) {
  const unsigned a = __float_as_uint(lo) + 0x8000u;
  const unsigned b = __float_as_uint(hi) + 0x8000u;
  return __builtin_amdgcn_perm(b, a, 0x07060302u);  // dst = [a.hi16, b.hi16]
}

__device__ __forceinline__ V16 pk8(f32x4 a, f32x4 b) {
  V16 v;
  v.u.x = pk(a[0], a[1]); v.u.y = pk(a[2], a[3]);
  v.u.z = pk(b[0], b[1]); v.u.w = pk(b[2], b[3]);
  return v;
}

// Single-barrier software pipeline:
//   iter i: compute tile i from xb[p] + store out DIRECTLY from q==0 lanes;
//           pack regs(tile i+1) -> xb[p^1]; __syncthreads();
//           global-load tile i+2 -> regs.
// out[b,k] = sigmoid(2*S) = 1/(1+2^(-L2E2*S)),
// S = b2 + sum_h w2 - sum_h 2*w2/(exp2(L2E2*(W1x)_h + L2E2*b1_h)+1)
// kb1 (=L2E2*b1) is folded into the MFMA C-operand init (no per-element add).
//
// LDS = xb only = 16384B (ob staging deleted; q==0 lanes hold the full reduced
// output after shfl_xor and store float2 straight to global; the 4 waves of a
// block jointly cover a contiguous 2KB out-tile so L2 merges the 32B-stride
// stores). Dropping ob also drops the swizzle temps -> VGPR pressure back to
// the 64 target so 8 blocks/CU (32 waves) can co-reside with zero tail round.
// launch_bounds MUST stay (256,4): (256,8) clamps the allocator to 32 arch
// VGPRs (unified-file split accounting) and spills everything (round-1: 833MB
// scratch fetch, 294us/dispatch).
__global__ __launch_bounds__(256, 4) void fused_mlp8(
    const float* __restrict__ x, const float* __restrict__ W1,
    const float* __restrict__ b1, const float* __restrict__ W2,
    const float* __restrict__ b2, float* __restrict__ out) {

  // x: 2 buffers x 64 rows x 8 chunks(16B); chunk c of row r at r*8 + (c ^ (r&7))
  __shared__ V16 xb[2][512];

  const int tid  = threadIdx.x;
  const int wave = tid >> 6;
  const int lane = tid & 63;
  const int m16  = lane & 15;
  const int q    = lane >> 4;

  // ---- W1 A-fragments (scaled by L2E2): lane holds rows n=(4w+mt)*16+m16
  short8 w1f[4][2];
#pragma unroll
  for (int mt = 0; mt < 4; ++mt) {
    const int n = (wave * 4 + mt) * 16 + m16;
#pragma unroll
    for (int ks = 0; ks < 2; ++ks) {
      const float* p = W1 + n * 64 + ks * 32 + q * 8;
      const f32x4 u0 = *(const f32x4*)p, u1 = *(const f32x4*)(p + 4);
      f32x4 s0, s1;
#pragma unroll
      for (int r = 0; r < 4; ++r) { s0[r] = L2E2 * u0[r]; s1[r] = L2E2 * u1[r]; }
      w1f[mt][ks] = pk8(s0, s1).s;
    }
  }

  // ---- folded per-lane constants for C-layout rows n0 = (4w+mt)*16 + 4q
  f32x4 kb1[4], w2m[4];
  float sw2[2] = {0.f, 0.f};
#pragma unroll
  for (int mt = 0; mt < 4; ++mt) {
    const int n0 = (wave * 4 + mt) * 16 + q * 4;
    const f32x4 b1x = *(const f32x4*)(b1 + n0);
    const f32x4 w2x = *(const f32x4*)(W2 + n0);
#pragma unroll
    for (int r = 0; r < 4; ++r) {
      kb1[mt][r] = L2E2 * b1x[r];
      w2m[mt][r] = -2.0f * w2x[r];
      sw2[mt >> 1] += w2x[r];
    }
  }
  float KSbn[2];   // -L2E2*(sum w2 + b2): out = rcp(exp2(fma(P,-L2E2,KSbn))+1)
#pragma unroll
  for (int j = 0; j < 2; ++j) {
    float s = sw2[j];
    s += __shfl_xor(s, 16);
    s += __shfl_xor(s, 32);
    KSbn[j] = -L2E2 * (s + b2[wave * 2 + j]);
  }

  // ---- staging geometry: thread covers row=tid>>2, cols seg*16..+15 (64B)
  const int srow = tid >> 2;
  const int seg  = tid & 3;
  const int sw   = srow & 7;
  const float* gbase = x + (long)srow * 64 + seg * 16;

  // ---- prologue: tile0 -> xb[0]; tile1 -> regs
  f32x4 pf[4];
#pragma unroll
  for (int c = 0; c < 4; ++c)
    pf[c] = *(const f32x4*)(gbase + (long)blockIdx.x * 4096 + c * 4);
  xb[0][srow * 8 + ((seg * 2)     ^ sw)] = pk8(pf[0], pf[1]);
  xb[0][srow * 8 + ((seg * 2 + 1) ^ sw)] = pk8(pf[2], pf[3]);
#pragma unroll
  for (int c = 0; c < 4; ++c)
    pf[c] = *(const f32x4*)(gbase + ((long)blockIdx.x + GRID) * 4096 + c * 4);
  __syncthreads();

#pragma unroll
  for (int i = 0; i < ITERS; ++i) {
    const int p = i & 1;
    const long tile = (long)blockIdx.x + (long)i * GRID;
    const long obase = tile * 512 + wave * 2;   // out floats, col = wave*2

    // ---- compute tile i from xb[p]; q==0 lanes store straight to global
#pragma unroll
    for (int tt = 0; tt < 4; ++tt) {
      const int r   = tt * 16 + m16;
      const int rsw = r & 7;
      const short8 xf0 = xb[p][r * 8 + (q       ^ rsw)].s;
      const short8 xf1 = xb[p][r * 8 + ((q + 4) ^ rsw)].s;

      f32x4 acc[4];
#pragma unroll
      for (int mt = 0; mt < 4; ++mt) {
        f32x4 z = kb1[mt];   // bias pre-folded as MFMA C-init
        z = __builtin_amdgcn_mfma_f32_16x16x32_bf16(w1f[mt][0], xf0, z, 0, 0, 0);
        z = __builtin_amdgcn_mfma_f32_16x16x32_bf16(w1f[mt][1], xf1, z, 0, 0, 0);
        acc[mt] = z;
      }

      float o0 = 0.f, o1 = 0.f;
#pragma unroll
      for (int j = 0; j < 2; ++j) {
        float P = 0.f;
#pragma unroll
        for (int t = 0; t < 2; ++t) {
          const int mt = j * 2 + t;
#pragma unroll
          for (int rr = 0; rr < 4; ++rr) {
            const float e = __builtin_amdgcn_exp2f(acc[mt][rr]);
            P = __builtin_fmaf(w2m[mt][rr], __builtin_amdgcn_rcpf(e + 1.0f), P);
          }
        }
        P += __shfl_xor(P, 16);
        P += __shfl_xor(P, 32);
        const float o = __builtin_amdgcn_rcpf(
            __builtin_amdgcn_exp2f(__builtin_fmaf(P, -L2E2, KSbn[j])) + 1.0f);
        if (j == 0) o0 = o; else o1 = o;
      }

      if (q == 0) {  // direct store: 16 lanes x 8B at 32B stride; L2 merges
        float2 st; st.x = o0; st.y = o1;
        *(float2*)(out + obase + (long)r * 8) = st;
      }
    }

    // ---- pack tile i+1 regs -> xb[p^1] (overlaps compute; pre-barrier)
    if (i + 1 < ITERS) {
      xb[p ^ 1][srow * 8 + ((seg * 2)     ^ sw)] = pk8(pf[0], pf[1]);
      xb[p ^ 1][srow * 8 + ((seg * 2 + 1) ^ sw)] = pk8(pf[2], pf[3]);
    }

    __syncthreads();   // the ONLY barrier per iteration

    // ---- issue tile i+2 loads; consumed at iteration i+1's pack
    if (i + 2 < ITERS) {
      const float* gp = gbase + (tile + 2 * GRID) * 4096;
#pragma unroll
      for (int c = 0; c < 4; ++c) pf[c] = *(const f32x4*)(gp + c * 4);
    }
  }
}

extern "C" void kernel_launch(void* const* d_in, const int* in_sizes, int n_in,
                              void* d_out, int out_size, void* d_ws, size_t ws_size,
                              hipStream_t stream) {
  const float* x  = (const float*)d_in[0];
  const float* W1 = (const float*)d_in[1];
  const float* b1 = (const float*)d_in[2];
  const float* W2 = (const float*)d_in[3];
  const float* b2 = (const float*)d_in[4];
  float* out = (float*)d_out;
  fused_mlp8<<<GRID, 256, 0, stream>>>(x, W1, b1, W2, b2, out);
}